// Round 1
// baseline (306.254 us; speedup 1.0000x reference)
//
#include <hip/hip_runtime.h>
#include <math.h>

#define NA 400000
#define NM 4
#define NP 512
#define ND 32
#define L2E 1.4426950408889634f
#define TPB 256
#define IPT 2
#define APB (TPB * IPT)                 // 512 atoms per block
#define BPM ((NA + APB - 1) / APB)      // 782 blocks per model (worst case)

// ---- workspace layout (bytes) ----
#define WS_ZSL 0                        // float [NM*NP*ND]   = 262144 B
#define WS_AZ  262144                   // float2[NM*NP]      = 16384 B
#define WS_ISL 278528                   // float [NM*ND]      = 512 B
#define WS_CNT 279040                   // int[4]
#define WS_OFF 279056                   // int[4]
#define WS_CUR 279072                   // int[4]
#define WS_BKT 279104                   // int[NA]            = 1.6 MB
// total ~1.88 MB

// ---------------- prep: scale inducing points, fold constants ----------------
// zs[p][d]  = Z[p][d] * exp(-0.5*log_ls[d])
// zsl[p][d] = zs * 2*L2E        (so dot(zsl, xs) = 2*L2E*(zs.xs))
// az[p]     = (alpha[p], L2E * ||zs[p]||^2)
// arg(p,n)  = dot - az.y - L2E*||xs||^2  = -L2E * dist  ->  exp2(arg) = exp(-dist)
__global__ void prep_kernel(const float* __restrict__ Z,
                            const float* __restrict__ alpha,
                            const float* __restrict__ lls,
                            float* __restrict__ zsl_w,
                            float2* __restrict__ az_w,
                            float* __restrict__ isl_w)
{
    int m = blockIdx.x;
    __shared__ float isl_s[ND];
    if (threadIdx.x < ND) {
        float v = expf(-0.5f * lls[m * ND + threadIdx.x]);
        isl_s[threadIdx.x] = v;
        isl_w[m * ND + threadIdx.x] = v;
    }
    __syncthreads();
    for (int p = threadIdx.x; p < NP; p += blockDim.x) {
        const float* zp = Z + (size_t)(m * NP + p) * ND;
        float row[ND];
        float z2 = 0.f;
#pragma unroll
        for (int d = 0; d < ND; ++d) {
            float zs = zp[d] * isl_s[d];
            row[d] = zs;
            z2 = fmaf(zs, zs, z2);
        }
        float* o = zsl_w + (size_t)(m * NP + p) * ND;
#pragma unroll
        for (int d = 0; d < ND; ++d) o[d] = row[d] * (2.0f * L2E);
        az_w[m * NP + p] = make_float2(alpha[m * NP + p], L2E * z2);
    }
}

// ---------------- histogram ----------------
__global__ void hist_kernel(const int* __restrict__ el, int* __restrict__ cnt)
{
    __shared__ int h[NM];
    if (threadIdx.x < NM) h[threadIdx.x] = 0;
    __syncthreads();
    int stride = gridDim.x * blockDim.x;
    for (int i = blockIdx.x * blockDim.x + threadIdx.x; i < NA; i += stride)
        atomicAdd(&h[el[i]], 1);
    __syncthreads();
    if (threadIdx.x < NM) atomicAdd(&cnt[threadIdx.x], h[threadIdx.x]);
}

// ---------------- tiny exclusive scan ----------------
__global__ void scan_kernel(const int* __restrict__ cnt,
                            int* __restrict__ off, int* __restrict__ cur)
{
    if (blockIdx.x == 0 && threadIdx.x == 0) {
        int o = 0;
        for (int m = 0; m < NM; ++m) { off[m] = o; cur[m] = o; o += cnt[m]; }
    }
}

// ---------------- scatter atoms into per-model buckets ----------------
__global__ void scatter_kernel(const int* __restrict__ el,
                               int* __restrict__ cur,
                               int* __restrict__ bucket)
{
    __shared__ int lcnt[NM];
    __shared__ int lbase[NM];
    if (threadIdx.x < NM) lcnt[threadIdx.x] = 0;
    __syncthreads();
    int i = blockIdx.x * blockDim.x + threadIdx.x;
    int e = 0, lpos = 0;
    bool act = (i < NA);
    if (act) { e = el[i]; lpos = atomicAdd(&lcnt[e], 1); }
    __syncthreads();
    if (threadIdx.x < NM) lbase[threadIdx.x] = atomicAdd(&cur[threadIdx.x], lcnt[threadIdx.x]);
    __syncthreads();
    if (act) bucket[lbase[e] + lpos] = i;
}

// ---------------- main compute ----------------
__global__ __launch_bounds__(TPB, 2)
void gpr_kernel(const float* __restrict__ x,
                const int* __restrict__ bucket,
                const float* __restrict__ zsl_w,
                const float2* __restrict__ az_w,
                const float* __restrict__ isl_w,
                const int* __restrict__ cnt,
                const int* __restrict__ off,
                float* __restrict__ out)
{
    __shared__ float4 zsl_s[NP * (ND / 4)];     // exactly 64 KiB

    int m = blockIdx.x & 3;
    int chunk = blockIdx.x >> 2;
    int c = cnt[m];
    if (chunk * APB >= c) return;               // uniform early exit (before any barrier)

    int tid = threadIdx.x;

    // stage this model's scaled inducing rows into LDS
    const float4* zg = (const float4*)(zsl_w + (size_t)m * NP * ND);
#pragma unroll
    for (int i = 0; i < (NP * ND / 4) / TPB; ++i)
        zsl_s[tid + i * TPB] = zg[tid + i * TPB];
    __syncthreads();

    // per-model lengthscale scales (wave-uniform)
    const float4* wlp = (const float4*)(isl_w + m * ND);
    float4 wv[ND / 4];
#pragma unroll
    for (int k = 0; k < ND / 4; ++k) wv[k] = wlp[k];

    int base = off[m];
    int n[IPT];
    float xs[IPT][ND];
    float x2l[IPT];
    float acc[IPT];

#pragma unroll
    for (int a = 0; a < IPT; ++a) {
        int j = chunk * APB + tid + a * TPB;
        n[a] = (j < c) ? bucket[base + j] : -1;
        acc[a] = 0.f;
        float s2 = 0.f;
        if (n[a] >= 0) {
            const float4* xp = (const float4*)(x + (size_t)n[a] * ND);
            float4 xv[ND / 4];
#pragma unroll
            for (int k = 0; k < ND / 4; ++k) xv[k] = xp[k];
#pragma unroll
            for (int k = 0; k < ND / 4; ++k) {
                xs[a][4 * k + 0] = xv[k].x * wv[k].x;
                xs[a][4 * k + 1] = xv[k].y * wv[k].y;
                xs[a][4 * k + 2] = xv[k].z * wv[k].z;
                xs[a][4 * k + 3] = xv[k].w * wv[k].w;
            }
#pragma unroll
            for (int d = 0; d < ND; ++d) s2 = fmaf(xs[a][d], xs[a][d], s2);
        } else {
#pragma unroll
            for (int d = 0; d < ND; ++d) xs[a][d] = 0.f;
        }
        x2l[a] = L2E * s2;
    }

    const float2* azp = az_w + m * NP;
    float acc_local[IPT];
#pragma unroll
    for (int a = 0; a < IPT; ++a) acc_local[a] = 0.f;

    for (int p = 0; p < NP; ++p) {
        float4 z[ND / 4];
        const float4* zr = &zsl_s[p * (ND / 4)];
#pragma unroll
        for (int k = 0; k < ND / 4; ++k) z[k] = zr[k];
        float2 az = azp[p];
#pragma unroll
        for (int a = 0; a < IPT; ++a) {
            float d0 = 0.f, d1 = 0.f, d2 = 0.f, d3 = 0.f;
#pragma unroll
            for (int k = 0; k < ND / 4; ++k) {
                d0 = fmaf(z[k].x, xs[a][4 * k + 0], d0);
                d1 = fmaf(z[k].y, xs[a][4 * k + 1], d1);
                d2 = fmaf(z[k].z, xs[a][4 * k + 2], d2);
                d3 = fmaf(z[k].w, xs[a][4 * k + 3], d3);
            }
            float arg = ((d0 + d1) + (d2 + d3)) - az.y - x2l[a];
            acc_local[a] = fmaf(az.x, __builtin_amdgcn_exp2f(arg), acc_local[a]);
        }
    }

#pragma unroll
    for (int a = 0; a < IPT; ++a) {
        acc[a] = acc_local[a];
        if (n[a] >= 0) out[n[a]] = acc[a];
    }
}

// ---------------- launch ----------------
extern "C" void kernel_launch(void* const* d_in, const int* in_sizes, int n_in,
                              void* d_out, int out_size, void* d_ws, size_t ws_size,
                              hipStream_t stream)
{
    const int*   element    = (const int*)d_in[0];
    const float* x          = (const float*)d_in[1];
    const float* inducing_x = (const float*)d_in[2];
    const float* alpha      = (const float*)d_in[3];
    const float* log_ls     = (const float*)d_in[4];
    float* out = (float*)d_out;

    char* ws = (char*)d_ws;
    float*  zsl_w = (float*)(ws + WS_ZSL);
    float2* az_w  = (float2*)(ws + WS_AZ);
    float*  isl_w = (float*)(ws + WS_ISL);
    int*    cnt   = (int*)(ws + WS_CNT);
    int*    off   = (int*)(ws + WS_OFF);
    int*    cur   = (int*)(ws + WS_CUR);
    int*    bkt   = (int*)(ws + WS_BKT);

    (void)in_sizes; (void)n_in; (void)out_size; (void)ws_size;

    hipMemsetAsync(cnt, 0, NM * sizeof(int), stream);

    prep_kernel<<<NM, 256, 0, stream>>>(inducing_x, alpha, log_ls, zsl_w, az_w, isl_w);
    hist_kernel<<<256, 256, 0, stream>>>(element, cnt);
    scan_kernel<<<1, 64, 0, stream>>>(cnt, off, cur);
    scatter_kernel<<<(NA + 1023) / 1024, 1024, 0, stream>>>(element, cur, bkt);
    gpr_kernel<<<NM * BPM, TPB, 0, stream>>>(x, bkt, zsl_w, az_w, isl_w, cnt, off, out);
}

// Round 2
// 98.606 us; speedup vs baseline: 3.1058x; 3.1058x over previous
//
#include <hip/hip_runtime.h>
#include <math.h>

#define NA 400000
#define NM 4
#define NP 512
#define ND 32
#define L2E 1.4426950408889634f
#define SQF 1.6986437f              /* sqrt(2*log2(e)); tiny error is a shared, consistent rescale */
#define TPB 512
#define APW 64                      /* atoms per wave (4 n-tiles of 16) */
#define APB 512                     /* atoms per block (8 waves) */
#define BPM ((NA + APB - 1) / APB)  /* 782 */
#define ACUT 60.0f                  /* skip exp when all args < -60 (terms < 2^-60) */

typedef __attribute__((ext_vector_type(8))) __bf16 bf16x8;
typedef __attribute__((ext_vector_type(8))) unsigned short us8;
typedef __attribute__((ext_vector_type(4))) float f32x4;

// ---- workspace layout (bytes) ----
#define WS_ZFRAG 0                  /* ushort [NM][32][2][512] = 262144 B  (MFMA A-fragment order) */
#define WS_AZ    262144             /* float2 [NM*512] = 16384 B  (alpha, 0.5*||Ahat||^2) */
#define WS_AZMIN 278528             /* float  [NM*32]  = 512 B   (per-ptile min of az.y) */
#define WS_ISL2  279040             /* float  [NM*32]  = 512 B   (exp(-ls/2)*SQF) */
#define WS_CNT   279552
#define WS_OFF   279568
#define WS_CUR   279584
#define WS_BKT   279616             /* int[NA] = 1.6 MB */

static __device__ __forceinline__ unsigned short rne_bf16(float f) {
    unsigned u = __builtin_bit_cast(unsigned, f);
    return (unsigned short)((u + 0x7fffu + ((u >> 16) & 1u)) >> 16);
}

// ---------------- prep: scale Z, bf16-split, permute to fragment order ----------------
__global__ void prep_kernel(const float* __restrict__ Z,
                            const float* __restrict__ alpha,
                            const float* __restrict__ lls,
                            unsigned short* __restrict__ zfrag,
                            float2* __restrict__ az,
                            float* __restrict__ azmin,
                            float* __restrict__ isl2)
{
    int m = blockIdx.x, tid = threadIdx.x;
    __shared__ float isl_s[ND];
    __shared__ float azy_s[NP];
    if (tid < ND) {
        float v = expf(-0.5f * lls[m * ND + tid]) * SQF;
        isl_s[tid] = v;
        isl2[m * ND + tid] = v;
    }
    __syncthreads();
    for (int p = tid; p < NP; p += blockDim.x) {
        const float* zp = Z + (size_t)(m * NP + p) * ND;
        int t = p >> 4, pl = p & 15;
        size_t fb = ((size_t)(m * 32 + t) * 2) * 512;
        float z2 = 0.f;
#pragma unroll
        for (int d = 0; d < ND; ++d) {
            float zs = zp[d] * isl_s[d];
            unsigned u  = __builtin_bit_cast(unsigned, zs);
            unsigned hu = u & 0xffff0000u;
            float hif   = __builtin_bit_cast(float, hu);
            float lof   = zs - hif;                      // exact
            unsigned short lo = rne_bf16(lof);
            float lof2  = __builtin_bit_cast(float, (unsigned)lo << 16);
            float zr    = hif + lof2;                    // reconstructed value actually used
            z2 = fmaf(zr, zr, z2);
            int lane = pl + 16 * (d >> 3), j = d & 7;    // A-frag: lane = m16 + 16*(k/8), elem j = k%8
            zfrag[fb +       lane * 8 + j] = (unsigned short)(hu >> 16);
            zfrag[fb + 512 + lane * 8 + j] = lo;
        }
        float y = 0.5f * z2;
        az[m * NP + p] = make_float2(alpha[m * NP + p], y);
        azy_s[p] = y;
    }
    __syncthreads();
    if (tid < 32) {
        float mn = 1e30f;
#pragma unroll
        for (int r = 0; r < 16; ++r) mn = fminf(mn, azy_s[tid * 16 + r]);
        azmin[m * 32 + tid] = mn;
    }
}

// ---------------- histogram ----------------
__global__ void hist_kernel(const int* __restrict__ el, int* __restrict__ cnt)
{
    __shared__ int h[NM];
    if (threadIdx.x < NM) h[threadIdx.x] = 0;
    __syncthreads();
    int stride = gridDim.x * blockDim.x;
    for (int i = blockIdx.x * blockDim.x + threadIdx.x; i < NA; i += stride)
        atomicAdd(&h[el[i]], 1);
    __syncthreads();
    if (threadIdx.x < NM) atomicAdd(&cnt[threadIdx.x], h[threadIdx.x]);
}

// ---------------- tiny exclusive scan ----------------
__global__ void scan_kernel(const int* __restrict__ cnt,
                            int* __restrict__ off, int* __restrict__ cur)
{
    if (blockIdx.x == 0 && threadIdx.x == 0) {
        int o = 0;
        for (int m = 0; m < NM; ++m) { off[m] = o; cur[m] = o; o += cnt[m]; }
    }
}

// ---------------- scatter atoms into per-model buckets ----------------
__global__ void scatter_kernel(const int* __restrict__ el,
                               int* __restrict__ cur,
                               int* __restrict__ bucket)
{
    __shared__ int lcnt[NM];
    __shared__ int lbase[NM];
    if (threadIdx.x < NM) lcnt[threadIdx.x] = 0;
    __syncthreads();
    int i = blockIdx.x * blockDim.x + threadIdx.x;
    int e = 0, lpos = 0;
    bool act = (i < NA);
    if (act) { e = el[i]; lpos = atomicAdd(&lcnt[e], 1); }
    __syncthreads();
    if (threadIdx.x < NM) lbase[threadIdx.x] = atomicAdd(&cur[threadIdx.x], lcnt[threadIdx.x]);
    __syncthreads();
    if (act) bucket[lbase[e] + lpos] = i;
}

// ---------------- main compute: bf16-split MFMA + exp-skip ----------------
__global__ __launch_bounds__(TPB, 4)
void gpr_kernel(const float* __restrict__ x,
                const int* __restrict__ bucket,
                const unsigned short* __restrict__ zfrag_w,
                const float2* __restrict__ az_w,
                const float* __restrict__ azmin_w,
                const float* __restrict__ isl2_w,
                const int* __restrict__ cnt_w,
                const int* __restrict__ off_w,
                float* __restrict__ out)
{
    __shared__ __align__(16) unsigned short zf[32][2][512];   // exactly 64 KiB

    int m = blockIdx.x & (NM - 1);
    int chunk = blockIdx.x >> 2;
    int c = cnt_w[m];
    if (chunk * APB >= c) return;                 // uniform, before any barrier

    int tid = threadIdx.x;

    // stage this model's fragment-ordered Z (64 KiB, linear copy)
    {
        const int4* zg = (const int4*)(zfrag_w + (size_t)m * 32768);
        int4* zs = (int4*)&zf[0][0][0];
#pragma unroll
        for (int i = 0; i < 8; ++i) zs[tid + i * TPB] = zg[tid + i * TPB];
    }
    __syncthreads();

    int wv = tid >> 6, lane = tid & 63;
    int lg = lane >> 4, ll = lane & 15;
    int base = off_w[m];
    int wbase = chunk * APB + wv * APW;
    if (wbase >= c) return;                       // no barriers after this point

    int k0 = lg * 8;
    const float4* wp = (const float4*)(isl2_w + m * ND + k0);
    float4 w0 = wp[0], w1 = wp[1];

    us8 Bh[4], Bl[4];
    float x2l[4], acc[4];
#pragma unroll
    for (int nt = 0; nt < 4; ++nt) {
        int j = wbase + nt * 16 + ll;
        int jj = (j < c) ? j : (c - 1);
        int n = bucket[base + jj];
        const float4* xp = (const float4*)(x + (size_t)n * ND + k0);
        float4 a = xp[0], b = xp[1];
        float xs[8] = {a.x * w0.x, a.y * w0.y, a.z * w0.z, a.w * w0.w,
                       b.x * w1.x, b.y * w1.y, b.z * w1.z, b.w * w1.w};
        float s2 = 0.f;
#pragma unroll
        for (int i = 0; i < 8; ++i) {
            unsigned u  = __builtin_bit_cast(unsigned, xs[i]);
            unsigned hu = u & 0xffff0000u;
            float hif   = __builtin_bit_cast(float, hu);
            float lof   = xs[i] - hif;            // exact
            unsigned short lo16 = rne_bf16(lof);
            Bh[nt][i] = (unsigned short)(hu >> 16);
            Bl[nt][i] = lo16;
            float xr = hif + __builtin_bit_cast(float, (unsigned)lo16 << 16);
            s2 = fmaf(xr, xr, s2);
        }
        s2 += __shfl_xor(s2, 16);
        s2 += __shfl_xor(s2, 32);
        x2l[nt] = 0.5f * s2;
        acc[nt] = 0.f;
    }
    float x2min = fminf(fminf(x2l[0], x2l[1]), fminf(x2l[2], x2l[3]));
    const float* azminp = azmin_w + m * 32;
    const float2* azbase = az_w + m * NP;

    for (int t = 0; t < 32; ++t) {
        bf16x8 Ah = *(const bf16x8*)&zf[t][0][lane * 8];
        bf16x8 Al = *(const bf16x8*)&zf[t][1][lane * 8];
        f32x4 cc[4];
#pragma unroll
        for (int nt = 0; nt < 4; ++nt) {
            bf16x8 bh = __builtin_bit_cast(bf16x8, Bh[nt]);
            bf16x8 bl = __builtin_bit_cast(bf16x8, Bl[nt]);
            f32x4 d = {0.f, 0.f, 0.f, 0.f};
            d = __builtin_amdgcn_mfma_f32_16x16x32_bf16(Al, bh, d, 0, 0, 0);
            d = __builtin_amdgcn_mfma_f32_16x16x32_bf16(Ah, bl, d, 0, 0, 0);
            d = __builtin_amdgcn_mfma_f32_16x16x32_bf16(Ah, bh, d, 0, 0, 0);
            cc[nt] = d;
        }
        float mx0 = fmaxf(fmaxf(cc[0][0], cc[0][1]), fmaxf(cc[0][2], cc[0][3]));
        float mx1 = fmaxf(fmaxf(cc[1][0], cc[1][1]), fmaxf(cc[1][2], cc[1][3]));
        float mx2 = fmaxf(fmaxf(cc[2][0], cc[2][1]), fmaxf(cc[2][2], cc[2][3]));
        float mx3 = fmaxf(fmaxf(cc[3][0], cc[3][1]), fmaxf(cc[3][2], cc[3][3]));
        float cmax = fmaxf(fmaxf(mx0, mx1), fmaxf(mx2, mx3));
        float bound = azminp[t] + x2min - ACUT;
        if (__any(cmax >= bound)) {
            // rows handled by this lane: p = 16t + 4*lg + r, r=0..3
            const float4* azp = (const float4*)(azbase + t * 16 + lg * 4);
            float4 az01 = azp[0], az23 = azp[1];   // (alpha0,y0,alpha1,y1), (alpha2,y2,alpha3,y3)
#pragma unroll
            for (int nt = 0; nt < 4; ++nt) {
                f32x4 d = cc[nt];
                float xl = x2l[nt];
                acc[nt] = fmaf(az01.x, __builtin_amdgcn_exp2f(d[0] - az01.y - xl), acc[nt]);
                acc[nt] = fmaf(az01.z, __builtin_amdgcn_exp2f(d[1] - az01.w - xl), acc[nt]);
                acc[nt] = fmaf(az23.x, __builtin_amdgcn_exp2f(d[2] - az23.y - xl), acc[nt]);
                acc[nt] = fmaf(az23.z, __builtin_amdgcn_exp2f(d[3] - az23.w - xl), acc[nt]);
            }
        }
    }

#pragma unroll
    for (int nt = 0; nt < 4; ++nt) {
        float v = acc[nt];
        v += __shfl_xor(v, 16);
        v += __shfl_xor(v, 32);
        if (lane < 16) {
            int j = wbase + nt * 16 + lane;
            if (j < c) out[bucket[base + j]] = v;
        }
    }
}

// ---------------- launch ----------------
extern "C" void kernel_launch(void* const* d_in, const int* in_sizes, int n_in,
                              void* d_out, int out_size, void* d_ws, size_t ws_size,
                              hipStream_t stream)
{
    const int*   element    = (const int*)d_in[0];
    const float* x          = (const float*)d_in[1];
    const float* inducing_x = (const float*)d_in[2];
    const float* alpha      = (const float*)d_in[3];
    const float* log_ls     = (const float*)d_in[4];
    float* out = (float*)d_out;

    char* ws = (char*)d_ws;
    unsigned short* zfrag = (unsigned short*)(ws + WS_ZFRAG);
    float2* az    = (float2*)(ws + WS_AZ);
    float*  azmin = (float*)(ws + WS_AZMIN);
    float*  isl2  = (float*)(ws + WS_ISL2);
    int*    cnt   = (int*)(ws + WS_CNT);
    int*    off   = (int*)(ws + WS_OFF);
    int*    cur   = (int*)(ws + WS_CUR);
    int*    bkt   = (int*)(ws + WS_BKT);

    (void)in_sizes; (void)n_in; (void)out_size; (void)ws_size;

    hipMemsetAsync(cnt, 0, NM * sizeof(int), stream);

    prep_kernel<<<NM, 256, 0, stream>>>(inducing_x, alpha, log_ls, zfrag, az, azmin, isl2);
    hist_kernel<<<256, 256, 0, stream>>>(element, cnt);
    scan_kernel<<<1, 64, 0, stream>>>(cnt, off, cur);
    scatter_kernel<<<(NA + 1023) / 1024, 1024, 0, stream>>>(element, cur, bkt);
    gpr_kernel<<<NM * BPM, TPB, 0, stream>>>(x, bkt, zfrag, az, azmin, isl2, cnt, off, out);
}